// Round 1
// 196.057 us; speedup vs baseline: 1.0532x; 1.0532x over previous
//
#include <hip/hip_runtime.h>
#include <math.h>

#define NN 50000
#define NE 800000
#define D  128
#define SCAN_CHUNK 1024
#define NSCAN ((NN + SCAN_CHUNK - 1) / SCAN_CHUNK)   // 49
#define PG_BLOCKS 782                                 // ceil((NE/4)/256)

typedef __attribute__((ext_vector_type(8))) short bf16x8;
typedef __attribute__((ext_vector_type(4))) float f32x4;

__device__ __forceinline__ unsigned short f32_to_bf16(float f) {
    unsigned u = __float_as_uint(f);
    u = u + 0x7FFFu + ((u >> 16) & 1u);   // RNE
    return (unsigned short)(u >> 16);
}

// ---- K1: degree atomics + per-edge rank; W bf16-frag pre-pack (block 0);
//      zero sentinel z-row NN (block 1); zero out-tail. Independent latency
//      streams overlap inside one kernel.
__global__ __launch_bounds__(256) void k_count(
        const float* __restrict__ Wg, const int* __restrict__ ei,
        int* __restrict__ deg, unsigned short* __restrict__ rank,
        unsigned short* __restrict__ wpk, unsigned short* __restrict__ zb,
        int* __restrict__ outtail, int tailN) {
    int tid = threadIdx.x;
    int g = blockIdx.x * 256 + tid;

    if (g < NE / 4) {
        int4 d4 = ((const int4*)(ei + NE))[g];
        ushort4 r;
        r.x = (unsigned short)atomicAdd(&deg[d4.x], 1);
        r.y = (unsigned short)atomicAdd(&deg[d4.y], 1);
        r.z = (unsigned short)atomicAdd(&deg[d4.z], 1);
        r.w = (unsigned short)atomicAdd(&deg[d4.w], 1);
        ((ushort4*)rank)[g] = r;
    }
    for (int i = g; i < tailN; i += PG_BLOCKS * 256) outtail[i] = 0;

    if (blockIdx.x == 0) {
        // output-linear: coalesced wpk stores, scattered (L2-cached) Wg reads.
        // frag = nt*256 + kt*64 + quad*16 + lo, elem j = k&7  (verified layout)
#pragma unroll 8
        for (int i = 0; i < 64; i++) {
            int o = i * 256 + tid;
            int j = o & 7, frag = o >> 3;
            int lo = frag & 15, quad = (frag >> 4) & 3;
            int kt = (frag >> 6) & 3, nt = frag >> 8;
            int k = kt * 32 + quad * 8 + j, n = nt * 16 + lo;
            wpk[o] = f32_to_bf16(Wg[k * 128 + n]);
        }
    }
    if (blockIdx.x == 1 && tid < 64)
        ((unsigned*)(zb + (size_t)NN * D))[tid] = 0u;   // sentinel row = 0
}

// ---- K2: fused scan (unchanged, proven): rowoff prefix-sum + dinv ----------
__global__ __launch_bounds__(256) void k_scan(const int* __restrict__ deg,
                                              int* __restrict__ partial,
                                              int* __restrict__ flag,
                                              int* __restrict__ rowoff,
                                              float* __restrict__ dinv) {
    __shared__ int sbuf[256];
    int t = threadIdx.x;
    int bid = blockIdx.x;
    int base = bid * SCAN_CHUNK + t * 4;
    int d[4]; int s = 0;
#pragma unroll
    for (int j = 0; j < 4; j++) {
        int i = base + j;
        d[j] = 0;
        if (i < NN) {
            d[j] = deg[i];
            s += d[j];
            dinv[i] = rsqrtf((float)d[j] + 1.0f);   // +1 self loop
        }
    }
    sbuf[t] = s; __syncthreads();
    for (int off = 1; off < 256; off <<= 1) {
        int v = (t >= off) ? sbuf[t - off] : 0;
        __syncthreads();
        sbuf[t] += v;
        __syncthreads();
    }
    if (t == 0) {
        atomicExch(&partial[bid], sbuf[255]);
        __threadfence();
        atomicAdd(flag, 1);
        while (atomicAdd(flag, 0) < NSCAN) {}   // 49 blocks co-resident: safe
    }
    __syncthreads();

    int lane = t & 63;
    int pv = (lane < NSCAN && lane < bid) ? atomicAdd(&partial[lane], 0) : 0;
#pragma unroll
    for (int off = 32; off > 0; off >>= 1) pv += __shfl_xor(pv, off, 64);

    int ex = sbuf[t] - s + pv;
#pragma unroll
    for (int j = 0; j < 4; j++) {
        int i = base + j;
        if (i < NN) {
            rowoff[i] = ex;
            ex += d[j];
            if (i == NN - 1) rowoff[NN] = ex;   // sentinel = NE
        }
    }
}

// ---- K3: z' = dinv ⊙ (h W) in bf16 + CSR fill, fused. No LDS, no barrier.
// B-frags stream from pre-packed wpk (L1-resident 32 KB, coalesced). The CSR
// scatter's gather/store latency hides under h loads + MFMA.
__global__ __launch_bounds__(256) void k_gemm_fill(
        const float* __restrict__ h, const uint4* __restrict__ wpk4,
        const int* __restrict__ ei, const unsigned short* __restrict__ rank,
        const int* __restrict__ rowoff, const float* __restrict__ dinv,
        unsigned short* __restrict__ zb, int* __restrict__ csr) {
    int tid = threadIdx.x;
    int g = blockIdx.x * 256 + tid;

    // CSR fill first: issue the random rowoff gathers as early as possible
    if (g < NE / 4) {
        int4 s4 = ((const int4*)ei)[g];
        int4 d4 = ((const int4*)(ei + NE))[g];
        ushort4 r4 = ((const ushort4*)rank)[g];
        csr[rowoff[d4.x] + r4.x] = s4.x;
        csr[rowoff[d4.y] + r4.y] = s4.y;
        csr[rowoff[d4.z] + r4.z] = s4.z;
        csr[rowoff[d4.w] + r4.w] = s4.w;
    }

    int w = tid >> 6, lane = tid & 63;
    int quad = lane >> 4, lo = lane & 15;
    int rowBase = blockIdx.x * 64 + w * 16;
    int rowA = rowBase + lo; if (rowA > NN - 1) rowA = NN - 1;
    const float4* h4 = (const float4*)h;

    bf16x8 af[4];
#pragma unroll
    for (int kt = 0; kt < 4; kt++) {
        float4 u = h4[(size_t)rowA * 32 + kt * 8 + quad * 2];
        float4 v = h4[(size_t)rowA * 32 + kt * 8 + quad * 2 + 1];
        bf16x8 a;
        a[0] = (short)f32_to_bf16(u.x); a[1] = (short)f32_to_bf16(u.y);
        a[2] = (short)f32_to_bf16(u.z); a[3] = (short)f32_to_bf16(u.w);
        a[4] = (short)f32_to_bf16(v.x); a[5] = (short)f32_to_bf16(v.y);
        a[6] = (short)f32_to_bf16(v.z); a[7] = (short)f32_to_bf16(v.w);
        af[kt] = a;
    }

    f32x4 acc[8];
#pragma unroll
    for (int nt = 0; nt < 8; nt++) acc[nt] = (f32x4){0.f, 0.f, 0.f, 0.f};

#pragma unroll
    for (int kt = 0; kt < 4; kt++) {
#pragma unroll
        for (int nt = 0; nt < 8; nt++) {
            uint4 tb = wpk4[nt * 256 + kt * 64 + lane];   // coalesced, L1-hit
            bf16x8 bfv = __builtin_bit_cast(bf16x8, tb);
            acc[nt] = __builtin_amdgcn_mfma_f32_16x16x32_bf16(af[kt], bfv, acc[nt], 0, 0, 0);
        }
    }

    // prescale by dinv[row] before the single bf16 rounding (same error
    // structure as unscaled-bf16 × fp32-weight: one rounding of an fp32 value)
#pragma unroll
    for (int reg = 0; reg < 4; reg++) {
        int row = rowBase + quad * 4 + reg;
        if (row < NN) {
            float dn = dinv[row];
#pragma unroll
            for (int nt = 0; nt < 8; nt++)
                zb[(size_t)row * D + nt * 16 + lo] = f32_to_bf16(acc[nt][reg] * dn);
        }
    }
}

// ---- K4: weightless gather + LN + tanh. Edge metadata on the SCALAR pipe
// (uniform csr addresses -> s_load, SGPR-base z gathers). 4 VALU ops/edge,
// no shfl, no dinv gather. Tail chunks clamp to sentinel row NN (zeros).
__global__ __launch_bounds__(256) void k_gather_ln(
        const int* __restrict__ rowoff, const int* __restrict__ csr,
        const float* __restrict__ dinv, const unsigned* __restrict__ zbu,
        const float* __restrict__ bias, const float* __restrict__ gamma,
        const float* __restrict__ beta, float* __restrict__ out) {
    int tid = threadIdx.x;
    int w = tid >> 6, lane = tid & 63;
    int rowBase = blockIdx.x * 16 + w * 4;

    float2 x[4];
#pragma unroll
    for (int r = 0; r < 4; r++) {
        int row = __builtin_amdgcn_readfirstlane(rowBase + r);
        float dn = dinv[row];
        unsigned zr = zbu[(size_t)row * 64 + lane];     // self loop: z' = dn*z
        float2 a;
        a.x = __uint_as_float(zr << 16);
        a.y = __uint_as_float(zr & 0xFFFF0000u);
        int cs = __builtin_amdgcn_readfirstlane(rowoff[row]);
        int ce = __builtin_amdgcn_readfirstlane(rowoff[row + 1]);
        for (int c = cs; c < ce; c += 8) {
            int m = ce - c;                             // uniform
            int s[8];
#pragma unroll
            for (int q = 0; q < 8; q++) {
                int t = csr[c + q];                     // s_load (uniform addr)
                s[q] = (q < m) ? t : NN;                // pad -> zero row
            }
            unsigned p[8];
#pragma unroll
            for (int q = 0; q < 8; q++)
                p[q] = zbu[(size_t)s[q] * 64 + lane];   // SGPR-base + lane*4
#pragma unroll
            for (int q = 0; q < 8; q++) {
                a.x += __uint_as_float(p[q] << 16);
                a.y += __uint_as_float(p[q] & 0xFFFF0000u);
            }
        }
        a.x *= dn; a.y *= dn;
        x[r] = a;
    }

    float2 bi = ((const float2*)bias)[lane];
    float2 ga = ((const float2*)gamma)[lane];
    float2 be = ((const float2*)beta)[lane];
#pragma unroll
    for (int r = 0; r < 4; r++) {
        int row = rowBase + r;
        float y0 = x[r].x + bi.x;
        float y1 = x[r].y + bi.y;
        float s = y0 + y1;
#pragma unroll
        for (int off = 32; off > 0; off >>= 1) s += __shfl_xor(s, off, 64);
        float m = s * (1.0f / 128.0f);
        float v0 = y0 - m, v1 = y1 - m;
        float vs = v0 * v0 + v1 * v1;
#pragma unroll
        for (int off = 32; off > 0; off >>= 1) vs += __shfl_xor(vs, off, 64);
        float rstd = rsqrtf(vs * (1.0f / 128.0f) + 1e-5f);
        float2 o;
        o.x = tanhf(v0 * rstd * ga.x + be.x);
        o.y = tanhf(v1 * rstd * ga.y + be.y);
        *(float2*)&out[(size_t)row * D + lane * 2] = o;
    }
}

extern "C" void kernel_launch(void* const* d_in, const int* in_sizes, int n_in,
                              void* d_out, int out_size, void* d_ws, size_t ws_size,
                              hipStream_t stream) {
    // inputs: t, h, edge_index, batch_size, W, b, gamma, beta
    const float* h     = (const float*)d_in[1];
    const int*   ei    = (const int*)  d_in[2];
    const float* Wg    = (const float*)d_in[4];
    const float* b     = (const float*)d_in[5];
    const float* gamma = (const float*)d_in[6];
    const float* beta  = (const float*)d_in[7];
    float* out = (float*)d_out;

    // workspace layout (~18.8 MB), all offsets alignment-checked
    char* wsb = (char*)d_ws;
    unsigned short* wpk    = (unsigned short*)(wsb);            // 32768 B (16B-aligned for uint4)
    int*            deg    = (int*)(wsb + 32768);               // NN ints
    int*            flag   = (int*)(wsb + 232768);              // 1 int (adjacent to deg)
    int*            partial= (int*)(wsb + 232832);              // 64 ints
    unsigned short* rank   = (unsigned short*)(wsb + 233088);   // NE ushorts (8B-aligned)
    int*            rowoff = (int*)(wsb + 1833088);             // NN+1 ints
    float*          dinv   = (float*)(wsb + 2633152);           // NN floats
    int*            csr    = (int*)(wsb + 2833152);             // NE ints
    unsigned short* zb     = (unsigned short*)(wsb + 6033152);  // (NN+1)*128 ushorts

    int tailN = out_size - NN * D;                 // int-zeros tail of d_out
    int* outtail = (int*)(out + (size_t)NN * D);

    hipMemsetAsync(deg, 0, NN * sizeof(int) + sizeof(int), stream);   // deg + flag
    k_count    <<<PG_BLOCKS, 256, 0, stream>>>(Wg, ei, deg, rank, wpk, zb, outtail, tailN);
    k_scan     <<<NSCAN,     256, 0, stream>>>(deg, partial, flag, rowoff, dinv);
    k_gemm_fill<<<PG_BLOCKS, 256, 0, stream>>>(h, (const uint4*)wpk, ei, rank, rowoff, dinv, zb, csr);
    k_gather_ln<<<NN / 16,   256, 0, stream>>>(rowoff, csr, dinv, (const unsigned*)zb, b, gamma, beta, out);
}